// Round 1
// baseline (584.379 us; speedup 1.0000x reference)
//
#include <hip/hip_runtime.h>
#include <math.h>

#define N_OBJ 16384
#define N_DIM 4096
#define NBINS 16384
#define K2_BLOCK 512
#define CHUNK (NBINS / K2_BLOCK)  // 32 bins per thread in the scan

// ---------- bin computation ----------
// Reference thresholds: t_m = fp32(fp32(m/16384) * 0.05f), m in [1,16384].
// b = min{m : p <= t_m};  returns b-1 in [0,16383], or -1 if p > 0.05f.
__device__ __forceinline__ int bin_of(float mu, float var) {
    const float inv_sqrt2 = 0.7071067811865476f;
    float z = (-mu / var) * inv_sqrt2;
    float p = 0.5f * (1.0f + erff(z));
    if (!(p <= 0.05f)) return -1;
    int m = (int)(p * 327680.0f);  // approx p / (0.05/16384); 327680 exact in fp32
    if (m < 1) m = 1;
    else if (m > NBINS) m = NBINS;
    // exact fixup against the reference's fp32 thresholds (1-2 iterations typ.)
    while (m > 1 && ((float)(m - 1) * (1.0f / 16384.0f)) * 0.05f >= p) --m;
    while (((float)m * (1.0f / 16384.0f)) * 0.05f < p) ++m;  // stops at m<=16384 since p<=0.05f=t(16384)
    return m - 1;
}

// ---------- block-wide scan of the 16384-bin histogram -> importance ----------
// hist32: NBINS/2 words, packed uint16 counts. Requires K2_BLOCK threads.
__device__ __forceinline__ void scan_and_output(unsigned int* hist32,
                                                unsigned int* wsum,
                                                unsigned int* rcnt,
                                                int* rfirst,
                                                float* out, int d) {
    const int tid = threadIdx.x;
    unsigned int vals[CHUNK];
    unsigned int lsum = 0;
#pragma unroll
    for (int i = 0; i < CHUNK / 2; ++i) {
        unsigned int w = hist32[tid * (CHUNK / 2) + i];
        unsigned int lo = w & 0xFFFFu, hi = w >> 16;
        vals[2 * i] = lo;
        vals[2 * i + 1] = hi;
        lsum += lo + hi;
    }
    // wave-inclusive scan of per-thread sums
    unsigned int incl = lsum;
#pragma unroll
    for (int off = 1; off < 64; off <<= 1) {
        unsigned int nbr = __shfl_up(incl, off, 64);
        if ((tid & 63) >= off) incl += nbr;
    }
    const int wave = tid >> 6, lane = tid & 63;
    if (lane == 63) wsum[wave] = incl;
    __syncthreads();
    unsigned int woff = 0;
    for (int w = 0; w < wave; ++w) woff += wsum[w];
    unsigned int run = woff + incl - lsum;  // exclusive prefix of this thread's chunk

    unsigned int matches = 0;
    int first = 0x7FFFFFFF;
#pragma unroll
    for (int i = 0; i < CHUNK; ++i) {
        run += vals[i];  // inclusive cnt at bin k
        int k = tid * CHUNK + i;
        if (run >= (unsigned int)(k + 1)) {
            ++matches;
            first = min(first, k);
        }
    }
#pragma unroll
    for (int off = 32; off >= 1; off >>= 1) {
        matches += __shfl_down(matches, off, 64);
        first = min(first, __shfl_down(first, off, 64));
    }
    if (lane == 0) { rcnt[wave] = matches; rfirst[wave] = first; }
    __syncthreads();
    if (tid == 0) {
        unsigned int tm = 0;
        int tf = 0x7FFFFFFF;
        for (int w = 0; w < K2_BLOCK / 64; ++w) { tm += rcnt[w]; tf = min(tf, rfirst[w]); }
        out[d] = (tf == 0x7FFFFFFF) ? 0.0f : (float)(tm + (unsigned int)tf);
    }
}

// ---------- K1: coalesced read, bin, transpose bins to [d][o] uint16 ----------
#define T_O 64
#define T_D 64
__global__ __launch_bounds__(256) void bins_transpose_kernel(
    const float* __restrict__ q_mu, const float* __restrict__ q_var,
    unsigned short* __restrict__ bins) {
    __shared__ unsigned short tile[T_O][T_D + 2];  // u16 stride 66 -> conflict-free column reads
    const int tid = threadIdx.x;
    const int dl = tid & 63;   // lane across d (coalesced global reads)
    const int r0 = tid >> 6;   // 0..3
    const int d0 = blockIdx.x * T_D;
    const int o0 = blockIdx.y * T_O;
#pragma unroll
    for (int r = r0; r < T_O; r += 4) {
        size_t idx = (size_t)(o0 + r) * N_DIM + (d0 + dl);
        float mu = q_mu[idx];
        float var = q_var[idx];
        int j = bin_of(mu, var);
        tile[r][dl] = (unsigned short)j;  // -1 -> 0xFFFF sentinel
    }
    __syncthreads();
    const int ol = tid & 63;   // lane across o (coalesced global writes)
    const int dd0 = tid >> 6;
#pragma unroll
    for (int dd = dd0; dd < T_D; dd += 4) {
        bins[(size_t)(d0 + dd) * N_OBJ + (o0 + ol)] = tile[ol][dd];
    }
}

// ---------- K2: per-column histogram + scan from transposed bins ----------
__global__ __launch_bounds__(K2_BLOCK) void hist_scan_kernel(
    const unsigned short* __restrict__ bins, float* __restrict__ out) {
    __shared__ unsigned int hist32[NBINS / 2];  // 32 KiB packed uint16 counts
    __shared__ unsigned int wsum[K2_BLOCK / 64];
    __shared__ unsigned int rcnt[K2_BLOCK / 64];
    __shared__ int rfirst[K2_BLOCK / 64];
    const int tid = threadIdx.x;
    const int d = blockIdx.x;
    for (int i = tid; i < NBINS / 2; i += K2_BLOCK) hist32[i] = 0u;
    __syncthreads();
    const uint4* src = (const uint4*)(bins + (size_t)d * N_OBJ);
#pragma unroll
    for (int it = 0; it < 4; ++it) {
        uint4 v = src[tid + it * K2_BLOCK];
        unsigned int wds[4] = {v.x, v.y, v.z, v.w};
#pragma unroll
        for (int q = 0; q < 4; ++q) {
            unsigned int w = wds[q];
            unsigned int j0 = w & 0xFFFFu, j1 = w >> 16;
            if (j0 != 0xFFFFu) atomicAdd(&hist32[j0 >> 1], 1u << ((j0 & 1) << 4));
            if (j1 != 0xFFFFu) atomicAdd(&hist32[j1 >> 1], 1u << ((j1 & 1) << 4));
        }
    }
    __syncthreads();
    scan_and_output(hist32, wsum, rcnt, rfirst, out, d);
}

// ---------- K0 fallback: fused strided-gather version (if ws too small) ----------
__global__ __launch_bounds__(K2_BLOCK) void fused_gather_kernel(
    const float* __restrict__ q_mu, const float* __restrict__ q_var,
    float* __restrict__ out) {
    __shared__ unsigned int hist32[NBINS / 2];
    __shared__ unsigned int wsum[K2_BLOCK / 64];
    __shared__ unsigned int rcnt[K2_BLOCK / 64];
    __shared__ int rfirst[K2_BLOCK / 64];
    const int tid = threadIdx.x;
    const int B = blockIdx.x;
    // XCD swizzle: consecutive columns on the same XCD so 64B lines are reused in one L2
    const int d = (B & 7) * (N_DIM / 8) + (B >> 3);
    for (int i = tid; i < NBINS / 2; i += K2_BLOCK) hist32[i] = 0u;
    __syncthreads();
    for (int o = tid; o < N_OBJ; o += K2_BLOCK) {
        size_t idx = (size_t)o * N_DIM + d;
        int j = bin_of(q_mu[idx], q_var[idx]);
        if (j >= 0) atomicAdd(&hist32[j >> 1], 1u << ((j & 1) << 4));
    }
    __syncthreads();
    scan_and_output(hist32, wsum, rcnt, rfirst, out, d);
}

extern "C" void kernel_launch(void* const* d_in, const int* in_sizes, int n_in,
                              void* d_out, int out_size, void* d_ws, size_t ws_size,
                              hipStream_t stream) {
    const float* q_mu = (const float*)d_in[0];
    const float* q_var = (const float*)d_in[1];
    float* out = (float*)d_out;
    const size_t need = (size_t)N_DIM * (size_t)N_OBJ * sizeof(unsigned short);  // 128 MiB
    if (ws_size >= need) {
        dim3 g1(N_DIM / T_D, N_OBJ / T_O);  // 64 x 256 blocks
        bins_transpose_kernel<<<g1, 256, 0, stream>>>(q_mu, q_var, (unsigned short*)d_ws);
        hist_scan_kernel<<<N_DIM, K2_BLOCK, 0, stream>>>((const unsigned short*)d_ws, out);
    } else {
        fused_gather_kernel<<<N_DIM, K2_BLOCK, 0, stream>>>(q_mu, q_var, out);
    }
}

// Round 2
// 576.145 us; speedup vs baseline: 1.0143x; 1.0143x over previous
//
#include <hip/hip_runtime.h>
#include <math.h>

#define N_OBJ 16384
#define N_DIM 4096
#define NBINS 16384
#define K2_BLOCK 512
#define CHUNK (NBINS / K2_BLOCK)  // 32 bins per thread in the scan

// ---------- fast bin computation ----------
// Reference: p = 0.5*(1+erf((-mu/var)/sqrt2)); thresholds t_m = fp32(fp32(m/16384)*0.05f).
// bin = min{m : p <= t_m} - 1, or -1 if p > 0.05f.
// Fast path: p = 0.5*erfc(x), x = (mu/var)/sqrt2, via Numerical-Recipes erfc
// (rel err ~1.2e-7 -> bin error << 1). Threshold slack (45.4) tolerates boundary flips.
__device__ __forceinline__ int bin_fast(float mu, float var) {
    float u = mu * __builtin_amdgcn_rcpf(var);       // ~1 ulp, var in [0.1,1]
    float x = u * 0.70710678f;                       // p = 0.5*erfc(x)
    bool maybe = (x >= 1.1630f);                     // p<=0.05 iff x>=1.16309; slop below
    float t = __builtin_amdgcn_rcpf(__builtin_fmaf(0.5f, x, 1.0f));
    float q = 0.17087277f;
    q = __builtin_fmaf(q, t, -0.82215223f);
    q = __builtin_fmaf(q, t, 1.48851587f);
    q = __builtin_fmaf(q, t, -1.13520398f);
    q = __builtin_fmaf(q, t, 0.27886807f);
    q = __builtin_fmaf(q, t, -0.18628806f);
    q = __builtin_fmaf(q, t, 0.09678418f);
    q = __builtin_fmaf(q, t, 0.37409196f);
    q = __builtin_fmaf(q, t, 1.00002368f);
    float ex = __builtin_fmaf(-x, x, -1.26551223f) + t * q;
    float p = maybe ? (0.5f * t * __expf(ex)) : 1.0f;  // invalid lanes forced out
    bool ok = (p <= 0.05f);
    float pc = fminf(p, 0.0625f);                    // keep int conversion in-range
    int m = (int)(pc * 327680.0f) + 1;               // ~ceil(p / (0.05/16384))
    m = (m > NBINS) ? NBINS : m;
    // one branchless correction vs the reference's exact fp32 thresholds
    float tm1 = ((float)(m - 1) * (1.0f / 16384.0f)) * 0.05f;
    m -= ((m > 1) && (tm1 >= p)) ? 1 : 0;
    return ok ? (m - 1) : -1;
}

// ---------- block-wide scan of the 16384-bin histogram -> importance ----------
// hist32: NBINS/2 packed-u16 words, stored at XOR-swizzled indices s^=(s>>5)&31.
__device__ __forceinline__ void scan_and_output(unsigned int* hist32,
                                                unsigned int* wsum,
                                                unsigned int* rcnt,
                                                int* rfirst,
                                                float* out, int d) {
    const int tid = threadIdx.x;
    unsigned int vals[CHUNK];
    unsigned int lsum = 0;
#pragma unroll
    for (int i = 0; i < CHUNK / 2; ++i) {
        unsigned int widx = (unsigned int)(tid * (CHUNK / 2) + i);
        widx ^= (widx >> 5) & 31u;                   // conflict-free: bank = i ^ ((tid>>1)&31)
        unsigned int w = hist32[widx];
        unsigned int lo = w & 0xFFFFu, hi = w >> 16;
        vals[2 * i] = lo;
        vals[2 * i + 1] = hi;
        lsum += lo + hi;
    }
    // wave-inclusive scan of per-thread sums
    unsigned int incl = lsum;
#pragma unroll
    for (int off = 1; off < 64; off <<= 1) {
        unsigned int nbr = __shfl_up(incl, off, 64);
        if ((tid & 63) >= off) incl += nbr;
    }
    const int wave = tid >> 6, lane = tid & 63;
    if (lane == 63) wsum[wave] = incl;
    __syncthreads();
    unsigned int woff = 0;
    for (int w = 0; w < wave; ++w) woff += wsum[w];
    unsigned int run = woff + incl - lsum;  // exclusive prefix of this thread's chunk

    unsigned int matches = 0;
    int first = 0x7FFFFFFF;
#pragma unroll
    for (int i = 0; i < CHUNK; ++i) {
        run += vals[i];  // inclusive cnt at bin k
        int k = tid * CHUNK + i;
        if (run >= (unsigned int)(k + 1)) {
            ++matches;
            first = min(first, k);
        }
    }
#pragma unroll
    for (int off = 32; off >= 1; off >>= 1) {
        matches += __shfl_down(matches, off, 64);
        first = min(first, __shfl_down(first, off, 64));
    }
    if (lane == 0) { rcnt[wave] = matches; rfirst[wave] = first; }
    __syncthreads();
    if (tid == 0) {
        unsigned int tm = 0;
        int tf = 0x7FFFFFFF;
        for (int w = 0; w < K2_BLOCK / 64; ++w) { tm += rcnt[w]; tf = min(tf, rfirst[w]); }
        out[d] = (tf == 0x7FFFFFFF) ? 0.0f : (float)(tm + (unsigned int)tf);
    }
}

// ---------- K1: float4 reads, fast bin, transpose bins to [d][o] uint16 ----------
#define T_O 64
#define T_D 64
__global__ __launch_bounds__(256) void bins_transpose_kernel(
    const float* __restrict__ q_mu, const float* __restrict__ q_var,
    unsigned short* __restrict__ bins) {
    __shared__ unsigned short tile[T_O][T_D + 4];  // stride 68 u16 = 136 B, 8B-aligned rows
    const int tid = threadIdx.x;
    const int d0 = blockIdx.x * T_D;
    const int o0 = blockIdx.y * T_O;
    const int dq = (tid & 15) * 4;   // lane's 4 consecutive d
    const int r0 = tid >> 4;         // 0..15
#pragma unroll
    for (int it = 0; it < 4; ++it) {
        const int r = r0 + it * 16;
        const size_t idx = (size_t)(o0 + r) * N_DIM + (d0 + dq);
        float4 mu4 = *(const float4*)(q_mu + idx);
        float4 va4 = *(const float4*)(q_var + idx);
        unsigned int b0 = (unsigned short)bin_fast(mu4.x, va4.x);
        unsigned int b1 = (unsigned short)bin_fast(mu4.y, va4.y);
        unsigned int b2 = (unsigned short)bin_fast(mu4.z, va4.z);
        unsigned int b3 = (unsigned short)bin_fast(mu4.w, va4.w);
        uint2 pk;
        pk.x = b0 | (b1 << 16);
        pk.y = b2 | (b3 << 16);
        *(uint2*)&tile[r][dq] = pk;
    }
    __syncthreads();
    const int ow = (tid & 15) * 4;   // lane's 4 consecutive o
    const int dbase = tid >> 4;      // 0..15
#pragma unroll
    for (int it = 0; it < 4; ++it) {
        const int dd = dbase + it * 16;
        unsigned int lo = (unsigned int)tile[ow + 0][dd] | ((unsigned int)tile[ow + 1][dd] << 16);
        unsigned int hi = (unsigned int)tile[ow + 2][dd] | ((unsigned int)tile[ow + 3][dd] << 16);
        uint2 pk; pk.x = lo; pk.y = hi;
        *(uint2*)(bins + (size_t)(d0 + dd) * N_OBJ + (o0 + ow)) = pk;
    }
}

// ---------- K2: per-column histogram + scan from transposed bins ----------
__global__ __launch_bounds__(K2_BLOCK) void hist_scan_kernel(
    const unsigned short* __restrict__ bins, float* __restrict__ out) {
    __shared__ unsigned int hist32[NBINS / 2];  // 32 KiB packed u16, XOR-swizzled
    __shared__ unsigned int wsum[K2_BLOCK / 64];
    __shared__ unsigned int rcnt[K2_BLOCK / 64];
    __shared__ int rfirst[K2_BLOCK / 64];
    const int tid = threadIdx.x;
    const int d = blockIdx.x;
    for (int i = tid; i < NBINS / 2; i += K2_BLOCK) hist32[i] = 0u;
    __syncthreads();
    const uint4* src = (const uint4*)(bins + (size_t)d * N_OBJ);
#pragma unroll
    for (int it = 0; it < 4; ++it) {
        uint4 v = src[tid + it * K2_BLOCK];
        unsigned int wds[4] = {v.x, v.y, v.z, v.w};
#pragma unroll
        for (int qi = 0; qi < 4; ++qi) {
            unsigned int w = wds[qi];
            unsigned int j0 = w & 0xFFFFu, j1 = w >> 16;
            if (j0 != 0xFFFFu) {
                unsigned int s = j0 >> 1; s ^= (s >> 5) & 31u;
                atomicAdd(&hist32[s], 1u << ((j0 & 1) << 4));
            }
            if (j1 != 0xFFFFu) {
                unsigned int s = j1 >> 1; s ^= (s >> 5) & 31u;
                atomicAdd(&hist32[s], 1u << ((j1 & 1) << 4));
            }
        }
    }
    __syncthreads();
    scan_and_output(hist32, wsum, rcnt, rfirst, out, d);
}

// ---------- K0 fallback: fused strided-gather version (if ws too small) ----------
__global__ __launch_bounds__(K2_BLOCK) void fused_gather_kernel(
    const float* __restrict__ q_mu, const float* __restrict__ q_var,
    float* __restrict__ out) {
    __shared__ unsigned int hist32[NBINS / 2];
    __shared__ unsigned int wsum[K2_BLOCK / 64];
    __shared__ unsigned int rcnt[K2_BLOCK / 64];
    __shared__ int rfirst[K2_BLOCK / 64];
    const int tid = threadIdx.x;
    const int B = blockIdx.x;
    const int d = (B & 7) * (N_DIM / 8) + (B >> 3);
    for (int i = tid; i < NBINS / 2; i += K2_BLOCK) hist32[i] = 0u;
    __syncthreads();
    for (int o = tid; o < N_OBJ; o += K2_BLOCK) {
        size_t idx = (size_t)o * N_DIM + d;
        int j = bin_fast(q_mu[idx], q_var[idx]);
        if (j >= 0) {
            unsigned int s = (unsigned int)j >> 1; s ^= (s >> 5) & 31u;
            atomicAdd(&hist32[s], 1u << ((j & 1) << 4));
        }
    }
    __syncthreads();
    scan_and_output(hist32, wsum, rcnt, rfirst, out, d);
}

extern "C" void kernel_launch(void* const* d_in, const int* in_sizes, int n_in,
                              void* d_out, int out_size, void* d_ws, size_t ws_size,
                              hipStream_t stream) {
    const float* q_mu = (const float*)d_in[0];
    const float* q_var = (const float*)d_in[1];
    float* out = (float*)d_out;
    const size_t need = (size_t)N_DIM * (size_t)N_OBJ * sizeof(unsigned short);  // 128 MiB
    if (ws_size >= need) {
        dim3 g1(N_DIM / T_D, N_OBJ / T_O);  // 64 x 256 blocks
        bins_transpose_kernel<<<g1, 256, 0, stream>>>(q_mu, q_var, (unsigned short*)d_ws);
        hist_scan_kernel<<<N_DIM, K2_BLOCK, 0, stream>>>((const unsigned short*)d_ws, out);
    } else {
        fused_gather_kernel<<<N_DIM, K2_BLOCK, 0, stream>>>(q_mu, q_var, out);
    }
}